// Round 4
// baseline (243.495 us; speedup 1.0000x reference)
//
#include <hip/hip_runtime.h>
#include <math.h>

#define KK 49
#define H 128
#define W 128
#define C 64
#define NB 4
#define EPS 1e-7f
#define PLANE (H * W)

#define TW 32             // tile width (pixels)
#define TH 4              // tile height (pixels)
#define HW2 38            // halo width  = TW + 6
#define HH2 10            // halo height = TH + 6
#define NPOS (HW2 * HH2)  // 380 halo positions
#define NP2 (2 * NPOS)    // 760 float4 slots per buffer (2 ch-halves of a pass)

// 512 threads, tile 32x4, FOUR threads per pixel (k-quartered 7x7 window):
//   w = tid&31 (pixel col), r = (tid>>5)&3 (pixel row), s2 = tid>>7 (k-quarter).
//   s2 owns k = s2*12 .. s2*12+11 (+k=48 for s2=3) -> 12-13 accumulators/thread.
// s2 is wave-uniform (waves 0-1: s2=0, ... 6-7: s2=3). Compute reads are two
// 32-lane-consecutive float4 groups per wave — R2-proven conflict-free shape
// (R3's 16-lane groups cost 3.4M conflict cycles).
// 8 channels staged per pass as 2 float4 halves (half-major layout), double-
// buffered LDS, register prefetch, norms accumulated by staging-slot owners.
// Softmax max/sum combined across the 4 k-quarters via a small LDS array.
__global__ __launch_bounds__(512, 4) void rsa_kernel(const float* __restrict__ x,
                                                     float* __restrict__ out) {
    __shared__ float4 sx[2][NP2];      // 24.3 KB: [buf][h*NPOS + pos]
    __shared__ float  sn2[NP2];        // 3.0 KB : per-half sum of squares
    __shared__ float  snf[NPOS];       // 1.5 KB : final norms
    __shared__ float  comb[4][TW * TH];// 2.0 KB : softmax cross-quarter combine

    const int tid = threadIdx.x;
    const int w   = tid & 31;
    const int r   = (tid >> 5) & 3;
    const int s2  = tid >> 7;          // wave-uniform
    const int w0  = blockIdx.x * TW;
    const int h0  = blockIdx.y * TH;
    const int b   = blockIdx.z;
    const float* __restrict__ xb = x + (size_t)b * C * PLANE;

    const bool has13 = (s2 == 3);
    const int  kbase = s2 * 12;

    // ---- per-thread window-address table (12-13 LDS float4 indices)
    const int caddr = (r + 3) * HW2 + (w + 3);
    int lofs[13];
#pragma unroll
    for (int l = 0; l < 13; ++l) {
        int k = kbase + l;
        if (l == 12 && !has13) { lofs[l] = caddr; continue; }
        int di = k / 7, dj = k - di * 7;
        lofs[l] = (r + di) * HW2 + (w + dj);
    }

    // ---- staging slot metadata (fixed across passes): slot i = tid + 512*j
    int goff[2], pos[2], hh[2];
    bool act[2], inb[2];
#pragma unroll
    for (int j = 0; j < 2; ++j) {
        int i = tid + j * 512;
        act[j] = (i < NP2);
        int ii = act[j] ? i : 0;
        int h  = (ii >= NPOS) ? 1 : 0;
        int p  = ii - h * NPOS;
        int rr = p / HW2, cc = p - rr * HW2;
        int gh = h0 - 3 + rr, gw = w0 - 3 + cc;
        inb[j]  = (gh >= 0) && (gh < H) && (gw >= 0) && (gw < W);
        goff[j] = gh * W + gw;
        pos[j]  = ii;                  // flat index within one buffer
        hh[j]   = h;                   // channel-half of the pass
    }

    float4 pf[2];
    float  np[2] = {0.f, 0.f};

    auto load_pass = [&](int t) {
#pragma unroll
        for (int j = 0; j < 2; ++j) {
            float4 v = make_float4(0.f, 0.f, 0.f, 0.f);
            if (act[j] && inb[j]) {
                const float* p = xb + (size_t)(t * 8 + hh[j] * 4) * PLANE + goff[j];
                v.x = p[0];
                v.y = p[PLANE];
                v.z = p[2 * PLANE];
                v.w = p[3 * PLANE];
            }
            pf[j] = v;
        }
    };

    auto write_pass = [&](int buf) {
#pragma unroll
        for (int j = 0; j < 2; ++j) {
            if (act[j]) {
                sx[buf][pos[j]] = pf[j];
                float4 v = pf[j];
                np[j] += v.x * v.x + v.y * v.y + v.z * v.z + v.w * v.w;
            }
        }
    };

    float acc[13];
#pragma unroll
    for (int l = 0; l < 13; ++l) acc[l] = 0.f;

    auto compute = [&](int buf) {
        const float4* __restrict__ base = sx[buf];
        const float4 c0 = base[caddr];
        const float4 c1 = base[NPOS + caddr];
#pragma unroll
        for (int l = 0; l < 13; ++l) {
            if (l < 12 || has13) {   // wave-uniform predicate
                const float4 n0 = base[lofs[l]];
                const float4 n1 = base[NPOS + lofs[l]];
                acc[l] += c0.x * n0.x; acc[l] += c0.y * n0.y;
                acc[l] += c0.z * n0.z; acc[l] += c0.w * n0.w;
                acc[l] += c1.x * n1.x; acc[l] += c1.y * n1.y;
                acc[l] += c1.z * n1.z; acc[l] += c1.w * n1.w;
            }
        }
    };

    // ---- software-pipelined main loop: prefetch t+1 while computing t
    load_pass(0);
    write_pass(0);
    __syncthreads();
#pragma unroll 2
    for (int t = 0; t < 8; ++t) {
        const int buf = t & 1;
        if (t < 7) load_pass(t + 1);
        compute(buf);
        if (t < 7) write_pass(buf ^ 1);
        __syncthreads();
    }

    // ---- norms: slot owners hold per-half sums over all 8 passes
#pragma unroll
    for (int j = 0; j < 2; ++j)
        if (act[j]) sn2[pos[j]] = np[j];
    __syncthreads();
    if (tid < NPOS) snf[tid] = sqrtf(sn2[tid] + sn2[tid + NPOS]);
    __syncthreads();

    // ---- cosine sim + cross-quarter softmax
    const int nk = has13 ? 13 : 12;
    const float nc = snf[caddr];
    float m = -1e30f;
#pragma unroll
    for (int l = 0; l < 13; ++l) {
        if (l < 12 || has13) {
            const float nn = snf[lofs[l]];
            const float sv = __fdividef(acc[l], nc * nn + EPS);
            acc[l] = sv;
            m = fmaxf(m, sv);
        }
    }
    const int pxi = r * TW + w;
    comb[s2][pxi] = m;
    __syncthreads();
    m = fmaxf(fmaxf(comb[0][pxi], comb[1][pxi]), fmaxf(comb[2][pxi], comb[3][pxi]));
    __syncthreads();

    float sum = 0.f;
#pragma unroll
    for (int l = 0; l < 13; ++l) {
        if (l < 12 || has13) {
            const float e = __expf(acc[l] - m);
            acc[l] = e;
            sum += e;
        }
    }
    comb[s2][pxi] = sum;
    __syncthreads();
    sum = (comb[0][pxi] + comb[1][pxi]) + (comb[2][pxi] + comb[3][pxi]);
    const float inv = __fdividef(1.f, sum);

    float* op = out + (((size_t)b * KK + kbase) << 14) + ((h0 + r) << 7) + (w0 + w);
#pragma unroll
    for (int l = 0; l < 13; ++l) {
        if (l < 12 || has13)
            op[(size_t)l << 14] = acc[l] * inv;
    }
}

extern "C" void kernel_launch(void* const* d_in, const int* in_sizes, int n_in,
                              void* d_out, int out_size, void* d_ws, size_t ws_size,
                              hipStream_t stream) {
    const float* x = (const float*)d_in[0];
    float* out = (float*)d_out;

    dim3 block(512, 1, 1);
    dim3 grid(W / TW, H / TH, NB);  // 4 x 32 x 4 = 512 blocks (2 per CU, 16 waves/CU)
    rsa_kernel<<<grid, block, 0, stream>>>(x, out);
}